// Round 1
// baseline (1014.676 us; speedup 1.0000x reference)
//
#include <hip/hip_runtime.h>
#include <hip/hip_bf16.h>

#define H 256
#define NTHREADS 256

// ---------- helpers ----------
static __device__ __forceinline__ float bf2f(unsigned short u) {
    return __uint_as_float(((unsigned int)u) << 16);
}
static __device__ __forceinline__ unsigned short f2bf(float f) {
    unsigned int x = __float_as_uint(f);
    unsigned int r = (x + 0x7fffu + ((x >> 16) & 1u)) >> 16;
    return (unsigned short)r;
}

typedef unsigned short us8 __attribute__((ext_vector_type(8)));
typedef __bf16 bf16x8 __attribute__((ext_vector_type(8)));
typedef float f32x4 __attribute__((ext_vector_type(4)));

// ---------- cast x (f32 -> bf16) into right half of Acat[m][512] ----------
__global__ __launch_bounds__(NTHREADS) void cast_x_kernel(
    const float* __restrict__ x, unsigned short* __restrict__ A, int n4)
{
    int i = blockIdx.x * NTHREADS + threadIdx.x;
    if (i < n4) {
        float4 v = ((const float4*)x)[i];
        ushort4 o;
        o.x = f2bf(v.x); o.y = f2bf(v.y); o.z = f2bf(v.z); o.w = f2bf(v.w);
        int m = i >> 6;          // 64 float4 per 256-col row
        int c = i & 63;
        ((ushort4*)(A + (size_t)m * 512 + H))[c] = o;
    }
}

// ---------- build Bcat[n][k], n in [0,256), k in [0,512): k<256 -> Wl[n][k], else Wr[n][k-256] ----------
__global__ __launch_bounds__(NTHREADS) void cast_w_kernel(
    const float* __restrict__ Wl, const float* __restrict__ Wr,
    unsigned short* __restrict__ Bcat)
{
    int i = blockIdx.x * NTHREADS + threadIdx.x;   // 256*512 elements
    int n = i >> 9;
    int k = i & 511;
    float v = (k < H) ? Wl[n * H + k] : Wr[n * H + (k - H)];
    Bcat[i] = f2bf(v);
}

// ---------- degree histogram ----------
__global__ __launch_bounds__(NTHREADS) void hist_kernel(
    const int* __restrict__ dst, int* __restrict__ cnt, int E)
{
    int i = blockIdx.x * NTHREADS + threadIdx.x;
    if (i < E) atomicAdd(&cnt[dst[i]], 1);
}

// ---------- multi-block exclusive scan, stage 1 ----------
__global__ __launch_bounds__(NTHREADS) void scan_partial_kernel(
    const int* __restrict__ cnt, int* __restrict__ row_ptr,
    int* __restrict__ blocksum, int n_nodes)
{
    __shared__ int tmp[NTHREADS];
    int t = threadIdx.x;
    int i = blockIdx.x * NTHREADS + t;
    int v = (i < n_nodes) ? cnt[i] : 0;
    tmp[t] = v;
    __syncthreads();
#pragma unroll
    for (int d = 1; d < NTHREADS; d <<= 1) {
        int add = (t >= d) ? tmp[t - d] : 0;
        __syncthreads();
        tmp[t] += add;
        __syncthreads();
    }
    if (i < n_nodes) row_ptr[i] = tmp[t] - v;   // exclusive
    if (t == NTHREADS - 1) blocksum[blockIdx.x] = tmp[t];
}

// ---------- stage 2 ----------
__global__ __launch_bounds__(NTHREADS) void scan_sums_kernel(
    int* __restrict__ blocksum, int* __restrict__ blockoff,
    int* __restrict__ row_ptr, int n_blocks, int n_nodes)
{
    __shared__ int tmp[NTHREADS];
    int t = threadIdx.x;
    int v = (t < n_blocks) ? blocksum[t] : 0;
    tmp[t] = v;
    __syncthreads();
#pragma unroll
    for (int d = 1; d < NTHREADS; d <<= 1) {
        int add = (t >= d) ? tmp[t - d] : 0;
        __syncthreads();
        tmp[t] += add;
        __syncthreads();
    }
    if (t < n_blocks) blockoff[t] = tmp[t] - v;
    if (t == NTHREADS - 1) row_ptr[n_nodes] = tmp[t];
}

// ---------- stage 3 ----------
__global__ __launch_bounds__(NTHREADS) void scan_finish_kernel(
    const int* __restrict__ cnt, int* __restrict__ row_ptr,
    int* __restrict__ cursor, float* __restrict__ deg_inv,
    const int* __restrict__ blockoff, int n_nodes)
{
    int i = blockIdx.x * NTHREADS + threadIdx.x;
    if (i < n_nodes) {
        int r = row_ptr[i] + blockoff[blockIdx.x];
        row_ptr[i] = r;
        cursor[i] = r;
        deg_inv[i] = 1.0f / (float)max(cnt[i], 1);
    }
}

// ---------- scatter edges into CSR order ----------
__global__ __launch_bounds__(NTHREADS) void fill_kernel(
    const int* __restrict__ src, const int* __restrict__ dst,
    int* __restrict__ cursor, int* __restrict__ csr_src, int E)
{
    int i = blockIdx.x * NTHREADS + threadIdx.x;
    if (i < E) {
        int p = atomicAdd(&cursor[dst[i]], 1);
        csr_src[p] = src[i];
    }
}

// ---------- feature-sliced mean-aggregate: gather h (right half of Acat) -> agg (left half) ----------
// slice = blockIdx.x % 8 keeps each XCD's gather working set (50000 x 64B = 3.2MB) L2-resident.
// One wave per node; lanes 0-31 = edge e, lanes 32-63 = edge e+1; 32 feats (one cache line).
__global__ __launch_bounds__(NTHREADS) void agg_kernel(
    const unsigned short* __restrict__ hsrc,   // Acat + 256 (h base)
    unsigned short* __restrict__ aggdst,       // Acat (agg base)
    const int* __restrict__ row_ptr, const int* __restrict__ csr_src,
    const float* __restrict__ deg_inv, int n_nodes)
{
    int bx = blockIdx.x;
    int slice = bx & 7;                // XCD-affine feature slice
    int nodeblk = bx >> 3;
    int wave = threadIdx.x >> 6;
    int lane = threadIdx.x & 63;
    int node = nodeblk * 4 + wave;
    if (node >= n_nodes) return;
    int half = lane >> 5;
    int feat = lane & 31;
    int beg = row_ptr[node];
    int cnt = row_ptr[node + 1] - beg;
    const unsigned short* hb = hsrc + (slice << 5) + feat;

    float acc = 0.f;
    int e = 0;
    for (; e + 4 <= cnt; e += 4) {
        int i0 = csr_src[beg + e + half];
        int i1 = csr_src[beg + e + 2 + half];
        float v0 = bf2f(hb[(size_t)i0 << 9]);
        float v1 = bf2f(hb[(size_t)i1 << 9]);
        acc += v0;
        acc += v1;
    }
    for (; e < cnt; e += 2) {
        int j = e + half;
        if (j < cnt) acc += bf2f(hb[(size_t)csr_src[beg + j] << 9]);
    }
    acc += __shfl_xor(acc, 32);
    if (half == 0) {
        unsigned short o = f2bf(acc * deg_inv[node]);
        __builtin_nontemporal_store(o, aggdst + (size_t)node * 512 + (slice << 5) + feat);
    }
}

// ---------- fused GEMM: out = ELU( Acat(M x 512) @ Bcat^T (256 x 512) + bias ) ----------
// K=512 (8 iterations), N=256 (2 j-tiles). XOR-swizzled LDS (conflict-free ds_read_b128).
// Output: bf16 into right half of next Acat (layers 1-2) or f32 final (layer 3).
__global__ __launch_bounds__(NTHREADS) void gemm_kernel(
    const unsigned short* __restrict__ Acat, const unsigned short* __restrict__ Bcat,
    const float* __restrict__ bias,
    unsigned short* __restrict__ outb, float* __restrict__ outf, int M)
{
    __shared__ __align__(16) unsigned short As[128 * 64];
    __shared__ __align__(16) unsigned short Bs[128 * 64];
    const int tid = threadIdx.x;
    const int lane = tid & 63;
    const int wave = tid >> 6;
    const int m0 = blockIdx.x * 128;
    const int j0 = blockIdx.y * 128;      // 2 n-tiles over N=256

    f32x4 acc[4][4] = {};

    const int wy = wave >> 1;
    const int wx = wave & 1;
    const int lrow = lane & 15;
    const int kchunk = lane >> 4;         // 0..3

    const int subrow = lane >> 3;
    const int cswz = (lane & 7) ^ (subrow & 7);

    for (int k0 = 0; k0 < 512; k0 += 64) {
#pragma unroll
        for (int r = 0; r < 4; ++r) {
            int ii = wave * 4 + r;                  // 8-row group index (0..15)
            int row = ii * 8 + subrow;
            int grow = min(m0 + row, M - 1);
            const unsigned short* ga = Acat + (size_t)grow * 512 + k0 + cswz * 8;
            __builtin_amdgcn_global_load_lds(
                (const __attribute__((address_space(1))) void*)ga,
                (__attribute__((address_space(3))) void*)(As + ii * 512), 16, 0, 0);
        }
#pragma unroll
        for (int r = 0; r < 4; ++r) {
            int ii = wave * 4 + r;
            int row = ii * 8 + subrow;
            const unsigned short* gb = Bcat + (size_t)(j0 + row) * 512 + k0 + cswz * 8;
            __builtin_amdgcn_global_load_lds(
                (const __attribute__((address_space(1))) void*)gb,
                (__attribute__((address_space(3))) void*)(Bs + ii * 512), 16, 0, 0);
        }
        __syncthreads();
#pragma unroll
        for (int kk2 = 0; kk2 < 64; kk2 += 32) {
            const int cid = (kk2 >> 3) + kchunk;    // chunk id 0..7
            bf16x8 a[4], b[4];
#pragma unroll
            for (int i2 = 0; i2 < 4; ++i2) {
                int row = wy * 64 + i2 * 16 + lrow;
                a[i2] = *(const bf16x8*)(As + row * 64 + ((cid ^ (row & 7)) << 3));
            }
#pragma unroll
            for (int jj = 0; jj < 4; ++jj) {
                int row = wx * 64 + jj * 16 + lrow;
                b[jj] = *(const bf16x8*)(Bs + row * 64 + ((cid ^ (row & 7)) << 3));
            }
#pragma unroll
            for (int i2 = 0; i2 < 4; ++i2)
#pragma unroll
                for (int jj = 0; jj < 4; ++jj)
                    acc[i2][jj] = __builtin_amdgcn_mfma_f32_16x16x32_bf16(
                        a[i2], b[jj], acc[i2][jj], 0, 0, 0);
        }
        __syncthreads();
    }

    // epilogue; D layout: col = lane&15, row = (lane>>4)*4 + reg
    const int rgrp = (lane >> 4) * 4;
    const bool fin = (outf != nullptr);
#pragma unroll
    for (int jj = 0; jj < 4; ++jj) {
        int n = j0 + wx * 64 + jj * 16 + lrow;
        float bn = bias[n];
#pragma unroll
        for (int i2 = 0; i2 < 4; ++i2) {
#pragma unroll
            for (int reg = 0; reg < 4; ++reg) {
                int m = m0 + wy * 64 + i2 * 16 + rgrp + reg;
                if (m < M) {
                    float v = acc[i2][jj][reg] + bn;
                    v = (v > 0.f) ? v : expm1f(v);
                    if (fin) outf[(size_t)m * H + n] = v;
                    else     outb[(size_t)m * 512 + H + n] = f2bf(v);
                }
            }
        }
    }
}

extern "C" void kernel_launch(void* const* d_in, const int* in_sizes, int n_in,
                              void* d_out, int out_size, void* d_ws, size_t ws_size,
                              hipStream_t stream) {
    const float* x = (const float*)d_in[0];
    const int* ei = (const int*)d_in[1];
    const float* W[6] = { (const float*)d_in[2], (const float*)d_in[3],
                          (const float*)d_in[4], (const float*)d_in[5],
                          (const float*)d_in[6], (const float*)d_in[7] };
    const float* bl[3] = { (const float*)d_in[8], (const float*)d_in[9],
                           (const float*)d_in[10] };
    float* out = (float*)d_out;

    const int N = in_sizes[0] / H;      // 50000
    const int E = in_sizes[1] / 2;      // 800000
    const int* src = ei;
    const int* dst = ei + E;

    // workspace carve (256B aligned)
    char* p = (char*)d_ws;
    auto carve = [&](size_t bytes) {
        char* q = p;
        p += (bytes + 255) & ~(size_t)255;
        return q;
    };
    int*            cnt      = (int*)carve((size_t)N * 4);
    int*            row_ptr  = (int*)carve((size_t)(N + 1) * 4);
    int*            cursor   = (int*)carve((size_t)N * 4);
    float*          deg_inv  = (float*)carve((size_t)N * 4);
    int*            csr_src  = (int*)carve((size_t)E * 4);
    int*            blocksum = (int*)carve((size_t)NTHREADS * 4);
    int*            blockoff = (int*)carve((size_t)NTHREADS * 4);
    unsigned short* Bcat     = (unsigned short*)carve((size_t)3 * H * 512 * 2);
    unsigned short* A0       = (unsigned short*)carve((size_t)N * 512 * 2);
    unsigned short* A1       = (unsigned short*)carve((size_t)N * 512 * 2);

    hipMemsetAsync(cnt, 0, (size_t)N * 4, stream);

    int n4 = N * H / 4;
    cast_x_kernel<<<(n4 + NTHREADS - 1) / NTHREADS, NTHREADS, 0, stream>>>(x, A0, n4);
    for (int l = 0; l < 3; ++l)
        cast_w_kernel<<<(H * 512) / NTHREADS, NTHREADS, 0, stream>>>(
            W[2 * l], W[2 * l + 1], Bcat + (size_t)l * H * 512);

    hist_kernel<<<(E + NTHREADS - 1) / NTHREADS, NTHREADS, 0, stream>>>(dst, cnt, E);

    int nb = (N + NTHREADS - 1) / NTHREADS;   // 196 <= 256
    scan_partial_kernel<<<nb, NTHREADS, 0, stream>>>(cnt, row_ptr, blocksum, N);
    scan_sums_kernel<<<1, NTHREADS, 0, stream>>>(blocksum, blockoff, row_ptr, nb, N);
    scan_finish_kernel<<<nb, NTHREADS, 0, stream>>>(cnt, row_ptr, cursor, deg_inv, blockoff, N);

    fill_kernel<<<(E + NTHREADS - 1) / NTHREADS, NTHREADS, 0, stream>>>(src, dst, cursor, csr_src, E);

    int mtiles = (N + 127) / 128;       // 391
    int nb_agg = 8 * ((N + 3) / 4);     // 8 slices x node-blocks (multiple of 8)
    unsigned short* cur = A0;
    unsigned short* nxt = A1;
    for (int l = 0; l < 3; ++l) {
        agg_kernel<<<nb_agg, NTHREADS, 0, stream>>>(
            cur + H, cur, row_ptr, csr_src, deg_inv, N);
        gemm_kernel<<<dim3(mtiles, 2), NTHREADS, 0, stream>>>(
            cur, Bcat + (size_t)l * H * 512, bl[l],
            nxt, (l == 2) ? out : nullptr, N);
        unsigned short* t = cur; cur = nxt; nxt = t;
    }
}

// Round 2
// 540.727 us; speedup vs baseline: 1.8765x; 1.8765x over previous
//
#include <hip/hip_runtime.h>
#include <hip/hip_bf16.h>

#define H 256
#define NTHREADS 256

// ---------- helpers ----------
static __device__ __forceinline__ float bf2f(unsigned short u) {
    return __uint_as_float(((unsigned int)u) << 16);
}
static __device__ __forceinline__ unsigned short f2bf(float f) {
    unsigned int x = __float_as_uint(f);
    unsigned int r = (x + 0x7fffu + ((x >> 16) & 1u)) >> 16;
    return (unsigned short)r;
}

typedef unsigned short us8 __attribute__((ext_vector_type(8)));
typedef __bf16 bf16x8 __attribute__((ext_vector_type(8)));
typedef float f32x4 __attribute__((ext_vector_type(4)));

// ---------- cast x (f32 -> bf16) into right half of Acat[m][512] ----------
__global__ __launch_bounds__(NTHREADS) void cast_x_kernel(
    const float* __restrict__ x, unsigned short* __restrict__ A, int n4)
{
    int i = blockIdx.x * NTHREADS + threadIdx.x;
    if (i < n4) {
        float4 v = ((const float4*)x)[i];
        ushort4 o;
        o.x = f2bf(v.x); o.y = f2bf(v.y); o.z = f2bf(v.z); o.w = f2bf(v.w);
        int m = i >> 6;          // 64 float4 per 256-col row
        int c = i & 63;
        ((ushort4*)(A + (size_t)m * 512 + H))[c] = o;
    }
}

// ---------- build Bcat[n][k], n in [0,256), k in [0,512): k<256 -> Wl[n][k], else Wr[n][k-256] ----------
__global__ __launch_bounds__(NTHREADS) void cast_w_kernel(
    const float* __restrict__ Wl, const float* __restrict__ Wr,
    unsigned short* __restrict__ Bcat)
{
    int i = blockIdx.x * NTHREADS + threadIdx.x;   // 256*512 elements
    int n = i >> 9;
    int k = i & 511;
    float v = (k < H) ? Wl[n * H + k] : Wr[n * H + (k - H)];
    Bcat[i] = f2bf(v);
}

// ---------- degree histogram ----------
__global__ __launch_bounds__(NTHREADS) void hist_kernel(
    const int* __restrict__ dst, int* __restrict__ cnt, int E)
{
    int i = blockIdx.x * NTHREADS + threadIdx.x;
    if (i < E) atomicAdd(&cnt[dst[i]], 1);
}

// ---------- multi-block exclusive scan, stage 1 ----------
__global__ __launch_bounds__(NTHREADS) void scan_partial_kernel(
    const int* __restrict__ cnt, int* __restrict__ row_ptr,
    int* __restrict__ blocksum, int n_nodes)
{
    __shared__ int tmp[NTHREADS];
    int t = threadIdx.x;
    int i = blockIdx.x * NTHREADS + t;
    int v = (i < n_nodes) ? cnt[i] : 0;
    tmp[t] = v;
    __syncthreads();
#pragma unroll
    for (int d = 1; d < NTHREADS; d <<= 1) {
        int add = (t >= d) ? tmp[t - d] : 0;
        __syncthreads();
        tmp[t] += add;
        __syncthreads();
    }
    if (i < n_nodes) row_ptr[i] = tmp[t] - v;   // exclusive
    if (t == NTHREADS - 1) blocksum[blockIdx.x] = tmp[t];
}

// ---------- stage 2 ----------
__global__ __launch_bounds__(NTHREADS) void scan_sums_kernel(
    int* __restrict__ blocksum, int* __restrict__ blockoff,
    int* __restrict__ row_ptr, int n_blocks, int n_nodes)
{
    __shared__ int tmp[NTHREADS];
    int t = threadIdx.x;
    int v = (t < n_blocks) ? blocksum[t] : 0;
    tmp[t] = v;
    __syncthreads();
#pragma unroll
    for (int d = 1; d < NTHREADS; d <<= 1) {
        int add = (t >= d) ? tmp[t - d] : 0;
        __syncthreads();
        tmp[t] += add;
        __syncthreads();
    }
    if (t < n_blocks) blockoff[t] = tmp[t] - v;
    if (t == NTHREADS - 1) row_ptr[n_nodes] = tmp[t];
}

// ---------- stage 3 ----------
__global__ __launch_bounds__(NTHREADS) void scan_finish_kernel(
    const int* __restrict__ cnt, int* __restrict__ row_ptr,
    int* __restrict__ cursor, float* __restrict__ deg_inv,
    const int* __restrict__ blockoff, int n_nodes)
{
    int i = blockIdx.x * NTHREADS + threadIdx.x;
    if (i < n_nodes) {
        int r = row_ptr[i] + blockoff[blockIdx.x];
        row_ptr[i] = r;
        cursor[i] = r;
        deg_inv[i] = 1.0f / (float)max(cnt[i], 1);
    }
}

// ---------- scatter edges into CSR order ----------
__global__ __launch_bounds__(NTHREADS) void fill_kernel(
    const int* __restrict__ src, const int* __restrict__ dst,
    int* __restrict__ cursor, int* __restrict__ csr_src, int E)
{
    int i = blockIdx.x * NTHREADS + threadIdx.x;
    if (i < E) {
        int p = atomicAdd(&cursor[dst[i]], 1);
        csr_src[p] = src[i];
    }
}

// ---------- mean-aggregate: gather h rows (right half of Acat) -> agg (left half) ----------
// One wave per node. Lanes 0-31 even edges, 32-63 odd edges; 8 feats (16B) per lane.
// 16-edge unroll keeps 8 x 16B gathers in flight per lane.
__global__ __launch_bounds__(NTHREADS) void agg_kernel(
    const unsigned short* __restrict__ hsrc,   // Acat + 256 (h base), row stride 512
    unsigned short* __restrict__ aggdst,       // Acat (agg base), row stride 512
    const int* __restrict__ row_ptr, const int* __restrict__ csr_src,
    const float* __restrict__ deg_inv, int n_nodes)
{
    int wave = threadIdx.x >> 6;
    int lane = threadIdx.x & 63;
    int node = blockIdx.x * 4 + wave;
    if (node >= n_nodes) return;
    int beg = row_ptr[node];
    int cnt = row_ptr[node + 1] - beg;
    const int half = lane >> 5;
    const int foff = (lane & 31) * 8;
    const unsigned short* hb = hsrc + foff;

    float a[8] = {0.f, 0.f, 0.f, 0.f, 0.f, 0.f, 0.f, 0.f};

    for (int e = 0; e < cnt; e += 64) {
        int rem = min(64, cnt - e);
        int idx = (lane < rem) ? csr_src[beg + e + lane] : 0;
        int j = 0;
        for (; j + 16 <= rem; j += 16) {
            int s0 = __shfl(idx, j + 0 + half);
            int s1 = __shfl(idx, j + 2 + half);
            int s2 = __shfl(idx, j + 4 + half);
            int s3 = __shfl(idx, j + 6 + half);
            int s4 = __shfl(idx, j + 8 + half);
            int s5 = __shfl(idx, j + 10 + half);
            int s6 = __shfl(idx, j + 12 + half);
            int s7 = __shfl(idx, j + 14 + half);
            us8 v0 = *(const us8*)(hb + ((size_t)s0 << 9));
            us8 v1 = *(const us8*)(hb + ((size_t)s1 << 9));
            us8 v2 = *(const us8*)(hb + ((size_t)s2 << 9));
            us8 v3 = *(const us8*)(hb + ((size_t)s3 << 9));
            us8 v4 = *(const us8*)(hb + ((size_t)s4 << 9));
            us8 v5 = *(const us8*)(hb + ((size_t)s5 << 9));
            us8 v6 = *(const us8*)(hb + ((size_t)s6 << 9));
            us8 v7 = *(const us8*)(hb + ((size_t)s7 << 9));
#pragma unroll
            for (int t = 0; t < 8; ++t) a[t] += bf2f(v0[t]);
#pragma unroll
            for (int t = 0; t < 8; ++t) a[t] += bf2f(v1[t]);
#pragma unroll
            for (int t = 0; t < 8; ++t) a[t] += bf2f(v2[t]);
#pragma unroll
            for (int t = 0; t < 8; ++t) a[t] += bf2f(v3[t]);
#pragma unroll
            for (int t = 0; t < 8; ++t) a[t] += bf2f(v4[t]);
#pragma unroll
            for (int t = 0; t < 8; ++t) a[t] += bf2f(v5[t]);
#pragma unroll
            for (int t = 0; t < 8; ++t) a[t] += bf2f(v6[t]);
#pragma unroll
            for (int t = 0; t < 8; ++t) a[t] += bf2f(v7[t]);
        }
        for (; j + 8 <= rem; j += 8) {
            int s0 = __shfl(idx, j + 0 + half);
            int s1 = __shfl(idx, j + 2 + half);
            int s2 = __shfl(idx, j + 4 + half);
            int s3 = __shfl(idx, j + 6 + half);
            us8 v0 = *(const us8*)(hb + ((size_t)s0 << 9));
            us8 v1 = *(const us8*)(hb + ((size_t)s1 << 9));
            us8 v2 = *(const us8*)(hb + ((size_t)s2 << 9));
            us8 v3 = *(const us8*)(hb + ((size_t)s3 << 9));
#pragma unroll
            for (int t = 0; t < 8; ++t) a[t] += bf2f(v0[t]);
#pragma unroll
            for (int t = 0; t < 8; ++t) a[t] += bf2f(v1[t]);
#pragma unroll
            for (int t = 0; t < 8; ++t) a[t] += bf2f(v2[t]);
#pragma unroll
            for (int t = 0; t < 8; ++t) a[t] += bf2f(v3[t]);
        }
        for (; j < rem; j += 2) {
            int jj = j + half;
            int s = __shfl(idx, (jj < rem) ? jj : j);
            if (jj < rem) {
                us8 v = *(const us8*)(hb + ((size_t)s << 9));
#pragma unroll
                for (int t = 0; t < 8; ++t) a[t] += bf2f(v[t]);
            }
        }
    }

#pragma unroll
    for (int t = 0; t < 8; ++t) a[t] += __shfl_xor(a[t], 32);

    if (half == 0) {
        float di = deg_inv[node];
        us8 o;
#pragma unroll
        for (int t = 0; t < 8; ++t) o[t] = f2bf(a[t] * di);
        *(us8*)(aggdst + (size_t)node * 512 + foff) = o;
    }
}

// ---------- fused GEMM: out = ELU( Acat(M x 512) @ Bcat^T (256 x 512) + bias ) ----------
// K=512 (8 iterations), N=256 (2 j-tiles). XOR-swizzled LDS (conflict-free ds_read_b128).
// Output: bf16 into right half of next Acat (layers 1-2) or f32 final (layer 3).
__global__ __launch_bounds__(NTHREADS) void gemm_kernel(
    const unsigned short* __restrict__ Acat, const unsigned short* __restrict__ Bcat,
    const float* __restrict__ bias,
    unsigned short* __restrict__ outb, float* __restrict__ outf, int M)
{
    __shared__ __align__(16) unsigned short As[128 * 64];
    __shared__ __align__(16) unsigned short Bs[128 * 64];
    const int tid = threadIdx.x;
    const int lane = tid & 63;
    const int wave = tid >> 6;
    const int m0 = blockIdx.x * 128;
    const int j0 = blockIdx.y * 128;      // 2 n-tiles over N=256

    f32x4 acc[4][4] = {};

    const int wy = wave >> 1;
    const int wx = wave & 1;
    const int lrow = lane & 15;
    const int kchunk = lane >> 4;         // 0..3

    const int subrow = lane >> 3;
    const int cswz = (lane & 7) ^ (subrow & 7);

    for (int k0 = 0; k0 < 512; k0 += 64) {
#pragma unroll
        for (int r = 0; r < 4; ++r) {
            int ii = wave * 4 + r;                  // 8-row group index (0..15)
            int row = ii * 8 + subrow;
            int grow = min(m0 + row, M - 1);
            const unsigned short* ga = Acat + (size_t)grow * 512 + k0 + cswz * 8;
            __builtin_amdgcn_global_load_lds(
                (const __attribute__((address_space(1))) void*)ga,
                (__attribute__((address_space(3))) void*)(As + ii * 512), 16, 0, 0);
        }
#pragma unroll
        for (int r = 0; r < 4; ++r) {
            int ii = wave * 4 + r;
            int row = ii * 8 + subrow;
            const unsigned short* gb = Bcat + (size_t)(j0 + row) * 512 + k0 + cswz * 8;
            __builtin_amdgcn_global_load_lds(
                (const __attribute__((address_space(1))) void*)gb,
                (__attribute__((address_space(3))) void*)(Bs + ii * 512), 16, 0, 0);
        }
        __syncthreads();
#pragma unroll
        for (int kk2 = 0; kk2 < 64; kk2 += 32) {
            const int cid = (kk2 >> 3) + kchunk;    // chunk id 0..7
            bf16x8 a[4], b[4];
#pragma unroll
            for (int i2 = 0; i2 < 4; ++i2) {
                int row = wy * 64 + i2 * 16 + lrow;
                a[i2] = *(const bf16x8*)(As + row * 64 + ((cid ^ (row & 7)) << 3));
            }
#pragma unroll
            for (int jj = 0; jj < 4; ++jj) {
                int row = wx * 64 + jj * 16 + lrow;
                b[jj] = *(const bf16x8*)(Bs + row * 64 + ((cid ^ (row & 7)) << 3));
            }
#pragma unroll
            for (int i2 = 0; i2 < 4; ++i2)
#pragma unroll
                for (int jj = 0; jj < 4; ++jj)
                    acc[i2][jj] = __builtin_amdgcn_mfma_f32_16x16x32_bf16(
                        a[i2], b[jj], acc[i2][jj], 0, 0, 0);
        }
        __syncthreads();
    }

    // epilogue; D layout: col = lane&15, row = (lane>>4)*4 + reg
    const int rgrp = (lane >> 4) * 4;
    const bool fin = (outf != nullptr);
#pragma unroll
    for (int jj = 0; jj < 4; ++jj) {
        int n = j0 + wx * 64 + jj * 16 + lrow;
        float bn = bias[n];
#pragma unroll
        for (int i2 = 0; i2 < 4; ++i2) {
#pragma unroll
            for (int reg = 0; reg < 4; ++reg) {
                int m = m0 + wy * 64 + i2 * 16 + rgrp + reg;
                if (m < M) {
                    float v = acc[i2][jj][reg] + bn;
                    v = (v > 0.f) ? v : expm1f(v);
                    if (fin) outf[(size_t)m * H + n] = v;
                    else     outb[(size_t)m * 512 + H + n] = f2bf(v);
                }
            }
        }
    }
}

extern "C" void kernel_launch(void* const* d_in, const int* in_sizes, int n_in,
                              void* d_out, int out_size, void* d_ws, size_t ws_size,
                              hipStream_t stream) {
    const float* x = (const float*)d_in[0];
    const int* ei = (const int*)d_in[1];
    const float* W[6] = { (const float*)d_in[2], (const float*)d_in[3],
                          (const float*)d_in[4], (const float*)d_in[5],
                          (const float*)d_in[6], (const float*)d_in[7] };
    const float* bl[3] = { (const float*)d_in[8], (const float*)d_in[9],
                           (const float*)d_in[10] };
    float* out = (float*)d_out;

    const int N = in_sizes[0] / H;      // 50000
    const int E = in_sizes[1] / 2;      // 800000
    const int* src = ei;
    const int* dst = ei + E;

    // workspace carve (256B aligned)
    char* p = (char*)d_ws;
    auto carve = [&](size_t bytes) {
        char* q = p;
        p += (bytes + 255) & ~(size_t)255;
        return q;
    };
    int*            cnt      = (int*)carve((size_t)N * 4);
    int*            row_ptr  = (int*)carve((size_t)(N + 1) * 4);
    int*            cursor   = (int*)carve((size_t)N * 4);
    float*          deg_inv  = (float*)carve((size_t)N * 4);
    int*            csr_src  = (int*)carve((size_t)E * 4);
    int*            blocksum = (int*)carve((size_t)NTHREADS * 4);
    int*            blockoff = (int*)carve((size_t)NTHREADS * 4);
    unsigned short* Bcat     = (unsigned short*)carve((size_t)3 * H * 512 * 2);
    unsigned short* A0       = (unsigned short*)carve((size_t)N * 512 * 2);
    unsigned short* A1       = (unsigned short*)carve((size_t)N * 512 * 2);

    hipMemsetAsync(cnt, 0, (size_t)N * 4, stream);

    int n4 = N * H / 4;
    cast_x_kernel<<<(n4 + NTHREADS - 1) / NTHREADS, NTHREADS, 0, stream>>>(x, A0, n4);
    for (int l = 0; l < 3; ++l)
        cast_w_kernel<<<(H * 512) / NTHREADS, NTHREADS, 0, stream>>>(
            W[2 * l], W[2 * l + 1], Bcat + (size_t)l * H * 512);

    hist_kernel<<<(E + NTHREADS - 1) / NTHREADS, NTHREADS, 0, stream>>>(dst, cnt, E);

    int nb = (N + NTHREADS - 1) / NTHREADS;   // 196 <= 256
    scan_partial_kernel<<<nb, NTHREADS, 0, stream>>>(cnt, row_ptr, blocksum, N);
    scan_sums_kernel<<<1, NTHREADS, 0, stream>>>(blocksum, blockoff, row_ptr, nb, N);
    scan_finish_kernel<<<nb, NTHREADS, 0, stream>>>(cnt, row_ptr, cursor, deg_inv, blockoff, N);

    fill_kernel<<<(E + NTHREADS - 1) / NTHREADS, NTHREADS, 0, stream>>>(src, dst, cursor, csr_src, E);

    int mtiles = (N + 127) / 128;       // 391
    unsigned short* cur = A0;
    unsigned short* nxt = A1;
    for (int l = 0; l < 3; ++l) {
        agg_kernel<<<(N + 3) / 4, NTHREADS, 0, stream>>>(
            cur + H, cur, row_ptr, csr_src, deg_inv, N);
        gemm_kernel<<<dim3(mtiles, 2), NTHREADS, 0, stream>>>(
            cur, Bcat + (size_t)l * H * 512, bl[l],
            nxt, (l == 2) ? out : nullptr, N);
        unsigned short* t = cur; cur = nxt; nxt = t;
    }
}